// Round 1
// baseline (1487.604 us; speedup 1.0000x reference)
//
#include <hip/hip_runtime.h>
#include <math.h>

// Sinkhorn-style fixed point:
//   kappa[b,i,j] = (pos_i.pos_j - 0.5|pos_i|^2 - 0.5|pos_j|^2)*log2e + lw_j*log2e   (fp16, 67MB, L3-resident)
//   100x: gamma_i = -log2 sum_j 2^(kappa_ij + phi_j);  phi = 0.5(phi+gamma)          (exp2 domain)
//   final: cross logsumexp vs target_pos, weighted reduce to 8 floats.

typedef _Float16 f16;
typedef _Float16 f16x4 __attribute__((ext_vector_type(4)));
typedef _Float16 f16x8 __attribute__((ext_vector_type(8)));

#define LOG2E 1.4426950408889634f
#define LN2   0.6931471805599453f

__device__ __forceinline__ float EX2(float x){
#if __has_builtin(__builtin_amdgcn_exp2f)
    return __builtin_amdgcn_exp2f(x);
#else
    float r; asm("v_exp_f32 %0, %1" : "=v"(r) : "v"(x)); return r;
#endif
}
__device__ __forceinline__ float LG2(float x){
#if __has_builtin(__builtin_amdgcn_logf)
    return __builtin_amdgcn_logf(x);   // v_log_f32 == log2
#else
    float r; asm("v_log_f32 %0, %1" : "=v"(r) : "v"(x)); return r;
#endif
}

// ---------------- prep: lam = lw*log2e, phi0 = 0, half-sum-of-squares per row ----
__global__ __launch_bounds__(256) void prep_kernel(
    const float* __restrict__ lw, const float* __restrict__ pos,
    const float* __restrict__ tpos, float* __restrict__ lam,
    float* __restrict__ phi0, float* __restrict__ pss, float* __restrict__ tss)
{
    int idx = blockIdx.x * 256 + threadIdx.x;   // 0..16383 (= B*2048)
    lam[idx]  = lw[idx] * LOG2E;
    phi0[idx] = 0.f;
    const float4* pr = (const float4*)(pos + (size_t)idx * 64);
    float s = 0.f;
    #pragma unroll
    for (int k = 0; k < 16; ++k){ float4 v = pr[k]; s += v.x*v.x + v.y*v.y + v.z*v.z + v.w*v.w; }
    pss[idx] = 0.5f * s;
    const float4* tr = (const float4*)(tpos + (size_t)idx * 64);
    float s2 = 0.f;
    #pragma unroll
    for (int k = 0; k < 16; ++k){ float4 v = tr[k]; s2 += v.x*v.x + v.y*v.y + v.z*v.z + v.w*v.w; }
    tss[idx] = 0.5f * s2;
}

// ---------------- build kappa (fp16, exp2 domain, lam folded in) -----------------
__global__ __launch_bounds__(256) void build_kself(
    const float* __restrict__ pos, const float* __restrict__ lam,
    const float* __restrict__ pss, f16* __restrict__ K)
{
    __shared__ __align__(16) float As[64][68];   // transposed: As[d][r]
    __shared__ __align__(16) float Bs[64][68];
    int b = blockIdx.z, it = blockIdx.y, jt = blockIdx.x;
    int t = threadIdx.x;
    const float* pA = pos + ((size_t)b * 2048 + it * 64) * 64;
    const float* pB = pos + ((size_t)b * 2048 + jt * 64) * 64;
    #pragma unroll
    for (int k = 0; k < 4; ++k){
        int n = t + (k << 8);
        int r = n >> 4, d4 = (n & 15) << 2;
        float4 av = *(const float4*)(pA + r * 64 + d4);
        As[d4+0][r] = av.x; As[d4+1][r] = av.y; As[d4+2][r] = av.z; As[d4+3][r] = av.w;
        float4 bv = *(const float4*)(pB + r * 64 + d4);
        Bs[d4+0][r] = bv.x; Bs[d4+1][r] = bv.y; Bs[d4+2][r] = bv.z; Bs[d4+3][r] = bv.w;
    }
    __syncthreads();
    int tx = t & 15, ty = t >> 4;
    float acc[4][4] = {};
    #pragma unroll 8
    for (int d = 0; d < 64; ++d){
        float4 a = *(const float4*)&As[d][ty << 2];
        float4 c = *(const float4*)&Bs[d][tx << 2];
        float aa[4] = {a.x, a.y, a.z, a.w};
        float bb[4] = {c.x, c.y, c.z, c.w};
        #pragma unroll
        for (int r = 0; r < 4; ++r)
            #pragma unroll
            for (int cc = 0; cc < 4; ++cc)
                acc[r][cc] += aa[r] * bb[cc];
    }
    float4 siv  = *(const float4*)(pss + b * 2048 + it * 64 + (ty << 2));
    float4 sjv  = *(const float4*)(pss + b * 2048 + jt * 64 + (tx << 2));
    float4 lamv = *(const float4*)(lam + b * 2048 + jt * 64 + (tx << 2));
    float si[4] = {siv.x, siv.y, siv.z, siv.w};
    float sj[4] = {sjv.x, sjv.y, sjv.z, sjv.w};
    float lm[4] = {lamv.x, lamv.y, lamv.z, lamv.w};
    #pragma unroll
    for (int r = 0; r < 4; ++r){
        f16x4 o;
        #pragma unroll
        for (int c = 0; c < 4; ++c)
            o[c] = (f16)((acc[r][c] - si[r] - sj[c]) * LOG2E + lm[c]);
        size_t row = (size_t)b * 2048 + it * 64 + (ty << 2) + r;
        *(f16x4*)(K + row * 2048 + jt * 64 + (tx << 2)) = o;
    }
}

// ---------------- one damped logsumexp iteration (exp2 domain) -------------------
__device__ __forceinline__ void proc8(f16x8 kv, const float* cc, float& m, float& s){
    float tv[8];
    #pragma unroll
    for (int e = 0; e < 8; ++e) tv[e] = (float)kv[e] + cc[e];
    float m01 = fmaxf(tv[0], tv[1]), m23 = fmaxf(tv[2], tv[3]);
    float m45 = fmaxf(tv[4], tv[5]), m67 = fmaxf(tv[6], tv[7]);
    float cm = fmaxf(fmaxf(m01, m23), fmaxf(m45, m67));
    float nm = fmaxf(m, cm);
    float a = 0.f;
    #pragma unroll
    for (int e = 0; e < 8; ++e) a += EX2(tv[e] - nm);
    s = s * EX2(m - nm) + a;
    m = nm;
}

__global__ __launch_bounds__(256, 4) void sink_iter(
    const f16* __restrict__ K, const float* __restrict__ phi_in,
    float* __restrict__ phi_out)
{
    int lane = threadIdx.x & 63;
    int gw = (blockIdx.x << 2) + (threadIdx.x >> 6);  // global wave id, 4 rows/wave
    int b  = gw >> 9;
    int i0 = (gw & 511) << 2;
    const float* phib = phi_in + (b << 11);
    float c[32];                                      // this lane's phi slice (reused 4 rows)
    #pragma unroll
    for (int k = 0; k < 4; ++k){
        float4 p0 = *(const float4*)(phib + k * 512 + lane * 8);
        float4 p1 = *(const float4*)(phib + k * 512 + lane * 8 + 4);
        c[k*8+0]=p0.x; c[k*8+1]=p0.y; c[k*8+2]=p0.z; c[k*8+3]=p0.w;
        c[k*8+4]=p1.x; c[k*8+5]=p1.y; c[k*8+6]=p1.z; c[k*8+7]=p1.w;
    }
    const f16* Kb = K + (((size_t)(b << 11) + i0) << 11) + lane * 8;
    #pragma unroll
    for (int r = 0; r < 4; ++r){
        const f16* Kr = Kb + ((size_t)r << 11);
        f16x8 kv0 = *(const f16x8*)(Kr);
        f16x8 kv1 = *(const f16x8*)(Kr + 512);
        f16x8 kv2 = *(const f16x8*)(Kr + 1024);
        f16x8 kv3 = *(const f16x8*)(Kr + 1536);
        float m = -__builtin_inff(), s = 0.f;
        proc8(kv0, c + 0,  m, s);
        proc8(kv1, c + 8,  m, s);
        proc8(kv2, c + 16, m, s);
        proc8(kv3, c + 24, m, s);
        float lm = m;
        #pragma unroll
        for (int mask = 32; mask; mask >>= 1) m = fmaxf(m, __shfl_xor(m, mask));
        s *= EX2(lm - m);
        #pragma unroll
        for (int mask = 32; mask; mask >>= 1) s += __shfl_xor(s, mask);
        float gamma = -(m + LG2(s));
        if (lane == 0) phi_out[(b << 11) + i0 + r] = 0.5f * (phib[i0 + r] + gamma);
    }
}

// ---------------- cross logsumexp + weighted reduce ------------------------------
__global__ __launch_bounds__(256) void cross_kernel(
    const float* __restrict__ tpos, const float* __restrict__ pos,
    const float* __restrict__ phi,  const float* __restrict__ lam,
    const float* __restrict__ tss,  const float* __restrict__ pss,
    const float* __restrict__ tlw,  float* __restrict__ out)
{
    __shared__ __align__(16) float As[64][68];
    __shared__ __align__(16) float Bs[64][68];
    __shared__ float red[16];
    int tt = blockIdx.x, b = blockIdx.y;
    int t = threadIdx.x, tx = t & 15, ty = t >> 4;
    const float* pA = tpos + ((size_t)b * 2048 + tt * 64) * 64;
    #pragma unroll
    for (int k = 0; k < 4; ++k){
        int n = t + (k << 8);
        int r = n >> 4, d4 = (n & 15) << 2;
        float4 av = *(const float4*)(pA + r * 64 + d4);
        As[d4+0][r] = av.x; As[d4+1][r] = av.y; As[d4+2][r] = av.z; As[d4+3][r] = av.w;
    }
    float4 sv = *(const float4*)(tss + b * 2048 + tt * 64 + (ty << 2));
    float sit[4] = {sv.x, sv.y, sv.z, sv.w};
    float m[4], s[4];
    #pragma unroll
    for (int r = 0; r < 4; ++r){ m[r] = -__builtin_inff(); s[r] = 0.f; }

    for (int jt = 0; jt < 32; ++jt){
        __syncthreads();
        const float* pB = pos + ((size_t)b * 2048 + jt * 64) * 64;
        #pragma unroll
        for (int k = 0; k < 4; ++k){
            int n = t + (k << 8);
            int r = n >> 4, d4 = (n & 15) << 2;
            float4 bv = *(const float4*)(pB + r * 64 + d4);
            Bs[d4+0][r] = bv.x; Bs[d4+1][r] = bv.y; Bs[d4+2][r] = bv.z; Bs[d4+3][r] = bv.w;
        }
        __syncthreads();
        float acc[4][4] = {};
        #pragma unroll 8
        for (int d = 0; d < 64; ++d){
            float4 a = *(const float4*)&As[d][ty << 2];
            float4 c = *(const float4*)&Bs[d][tx << 2];
            float aa[4] = {a.x, a.y, a.z, a.w};
            float bb[4] = {c.x, c.y, c.z, c.w};
            #pragma unroll
            for (int r = 0; r < 4; ++r)
                #pragma unroll
                for (int cc = 0; cc < 4; ++cc)
                    acc[r][cc] += aa[r] * bb[cc];
        }
        float4 v1 = *(const float4*)(pss + b * 2048 + jt * 64 + (tx << 2));
        float4 v2 = *(const float4*)(phi + b * 2048 + jt * 64 + (tx << 2));
        float4 v3 = *(const float4*)(lam + b * 2048 + jt * 64 + (tx << 2));
        float sj[4] = {v1.x, v1.y, v1.z, v1.w};
        float cj[4] = {v2.x + v3.x, v2.y + v3.y, v2.z + v3.z, v2.w + v3.w};
        #pragma unroll
        for (int r = 0; r < 4; ++r){
            float tv[4];
            #pragma unroll
            for (int c = 0; c < 4; ++c)
                tv[c] = (acc[r][c] - sit[r] - sj[c]) * LOG2E + cj[c];
            float cm = fmaxf(fmaxf(tv[0], tv[1]), fmaxf(tv[2], tv[3]));
            float nm = fmaxf(m[r], cm);
            s[r] = s[r] * EX2(m[r] - nm)
                 + EX2(tv[0] - nm) + EX2(tv[1] - nm) + EX2(tv[2] - nm) + EX2(tv[3] - nm);
            m[r] = nm;
        }
    }
    // combine (m,s) across the 16 tx lanes owning the same rows
    #pragma unroll
    for (int r = 0; r < 4; ++r){
        #pragma unroll
        for (int mask = 8; mask; mask >>= 1){
            float om = __shfl_xor(m[r], mask);
            float os = __shfl_xor(s[r], mask);
            float nm = fmaxf(m[r], om);
            s[r] = s[r] * EX2(m[r] - nm) + os * EX2(om - nm);
            m[r] = nm;
        }
    }
    float part = 0.f;
    if (tx == 0){
        #pragma unroll
        for (int r = 0; r < 4; ++r){
            float gnat = -(m[r] + LG2(s[r])) * LN2;
            float w = EX2(tlw[b * 2048 + tt * 64 + (ty << 2) + r] * LOG2E);
            part += gnat * w;
        }
        red[ty] = part;
    }
    __syncthreads();
    if (t == 0){
        float tot = 0.f;
        #pragma unroll
        for (int i = 0; i < 16; ++i) tot += red[i];
        atomicAdd(out + b, tot);
    }
}

// ---------------- launch ---------------------------------------------------------
extern "C" void kernel_launch(void* const* d_in, const int* in_sizes, int n_in,
                              void* d_out, int out_size, void* d_ws, size_t ws_size,
                              hipStream_t stream)
{
    const float* pos  = (const float*)d_in[0];
    const float* lw   = (const float*)d_in[1];
    const float* tpos = (const float*)d_in[2];
    const float* tlw  = (const float*)d_in[3];
    float* out = (float*)d_out;

    char* ws = (char*)d_ws;
    f16* K = (f16*)ws;
    size_t off = (size_t)8 * 2048 * 2048 * 2;          // 67,108,864 B
    float* phi0 = (float*)(ws + off); off += 65536;
    float* phi1 = (float*)(ws + off); off += 65536;
    float* lam  = (float*)(ws + off); off += 65536;
    float* pss  = (float*)(ws + off); off += 65536;
    float* tss  = (float*)(ws + off); off += 65536;

    prep_kernel<<<64, 256, 0, stream>>>(lw, pos, tpos, lam, phi0, pss, tss);
    build_kself<<<dim3(32, 32, 8), 256, 0, stream>>>(pos, lam, pss, K);

    float* pin = phi0; float* pout = phi1;
    for (int it = 0; it < 100; ++it){
        sink_iter<<<1024, 256, 0, stream>>>(K, pin, pout);
        float* tmp = pin; pin = pout; pout = tmp;
    }
    hipMemsetAsync(d_out, 0, out_size * sizeof(float), stream);
    cross_kernel<<<dim3(32, 8), 256, 0, stream>>>(tpos, pos, pin, lam, tss, pss, tlw, out);
}

// Round 2
// 1404.950 us; speedup vs baseline: 1.0588x; 1.0588x over previous
//
#include <hip/hip_runtime.h>
#include <math.h>

// Sinkhorn-style fixed point, exp2 domain throughout:
//   K[b,i,j] = (pos_i.pos_j - ss_i - ss_j)*log2e + lw_j*log2e   (fp16, 67MB)
//   100x: gamma_i = -log2 sum_j 2^(K_ij + phi_j);  phi = 0.5(phi+gamma)
//   (no online max: t in [-160,+55] is safe in f32 exp2; every row holds its
//    diagonal term ~lambda_i so the sum never underflows to zero)
//   final: cross logsumexp vs target_pos (j-split 4x + finish reduce).

typedef _Float16 f16;
typedef _Float16 f16x4 __attribute__((ext_vector_type(4)));
typedef _Float16 f16x8 __attribute__((ext_vector_type(8)));

#define LOG2E 1.4426950408889634f
#define LN2   0.6931471805599453f

__device__ __forceinline__ float EX2(float x){
#if __has_builtin(__builtin_amdgcn_exp2f)
    return __builtin_amdgcn_exp2f(x);
#else
    float r; asm("v_exp_f32 %0, %1" : "=v"(r) : "v"(x)); return r;
#endif
}
__device__ __forceinline__ float LG2(float x){
#if __has_builtin(__builtin_amdgcn_logf)
    return __builtin_amdgcn_logf(x);   // v_log_f32 == log2
#else
    float r; asm("v_log_f32 %0, %1" : "=v"(r) : "v"(x)); return r;
#endif
}

// ---------------- prep: lam = lw*log2e, phi0 = 0, half-sum-of-squares per row ----
__global__ __launch_bounds__(256) void prep_kernel(
    const float* __restrict__ lw, const float* __restrict__ pos,
    const float* __restrict__ tpos, float* __restrict__ lam,
    float* __restrict__ phi0, float* __restrict__ pss, float* __restrict__ tss)
{
    int idx = blockIdx.x * 256 + threadIdx.x;   // 0..16383 (= B*2048)
    lam[idx]  = lw[idx] * LOG2E;
    phi0[idx] = 0.f;
    const float4* pr = (const float4*)(pos + (size_t)idx * 64);
    float s = 0.f;
    #pragma unroll
    for (int k = 0; k < 16; ++k){ float4 v = pr[k]; s += v.x*v.x + v.y*v.y + v.z*v.z + v.w*v.w; }
    pss[idx] = 0.5f * s;
    const float4* tr = (const float4*)(tpos + (size_t)idx * 64);
    float s2 = 0.f;
    #pragma unroll
    for (int k = 0; k < 16; ++k){ float4 v = tr[k]; s2 += v.x*v.x + v.y*v.y + v.z*v.z + v.w*v.w; }
    tss[idx] = 0.5f * s2;
}

// ---------------- build kappa (fp16, exp2 domain, lam folded in) -----------------
__global__ __launch_bounds__(256) void build_kself(
    const float* __restrict__ pos, const float* __restrict__ lam,
    const float* __restrict__ pss, f16* __restrict__ K)
{
    __shared__ __align__(16) float As[64][68];   // transposed: As[d][r]
    __shared__ __align__(16) float Bs[64][68];
    int b = blockIdx.z, it = blockIdx.y, jt = blockIdx.x;
    int t = threadIdx.x;
    const float* pA = pos + ((size_t)b * 2048 + it * 64) * 64;
    const float* pB = pos + ((size_t)b * 2048 + jt * 64) * 64;
    #pragma unroll
    for (int k = 0; k < 4; ++k){
        int n = t + (k << 8);
        int r = n >> 4, d4 = (n & 15) << 2;
        float4 av = *(const float4*)(pA + r * 64 + d4);
        As[d4+0][r] = av.x; As[d4+1][r] = av.y; As[d4+2][r] = av.z; As[d4+3][r] = av.w;
        float4 bv = *(const float4*)(pB + r * 64 + d4);
        Bs[d4+0][r] = bv.x; Bs[d4+1][r] = bv.y; Bs[d4+2][r] = bv.z; Bs[d4+3][r] = bv.w;
    }
    __syncthreads();
    int tx = t & 15, ty = t >> 4;
    float acc[4][4] = {};
    #pragma unroll 8
    for (int d = 0; d < 64; ++d){
        float4 a = *(const float4*)&As[d][ty << 2];
        float4 c = *(const float4*)&Bs[d][tx << 2];
        float aa[4] = {a.x, a.y, a.z, a.w};
        float bb[4] = {c.x, c.y, c.z, c.w};
        #pragma unroll
        for (int r = 0; r < 4; ++r)
            #pragma unroll
            for (int cc = 0; cc < 4; ++cc)
                acc[r][cc] += aa[r] * bb[cc];
    }
    float4 siv  = *(const float4*)(pss + b * 2048 + it * 64 + (ty << 2));
    float4 sjv  = *(const float4*)(pss + b * 2048 + jt * 64 + (tx << 2));
    float4 lamv = *(const float4*)(lam + b * 2048 + jt * 64 + (tx << 2));
    float si[4] = {siv.x, siv.y, siv.z, siv.w};
    float sj[4] = {sjv.x, sjv.y, sjv.z, sjv.w};
    float lm[4] = {lamv.x, lamv.y, lamv.z, lamv.w};
    #pragma unroll
    for (int r = 0; r < 4; ++r){
        f16x4 o;
        #pragma unroll
        for (int c = 0; c < 4; ++c)
            o[c] = (f16)((acc[r][c] - si[r] - sj[c]) * LOG2E + lm[c]);
        size_t row = (size_t)b * 2048 + it * 64 + (ty << 2) + r;
        *(f16x4*)(K + row * 2048 + jt * 64 + (tx << 2)) = o;
    }
}

// ---------------- one damped iteration: direct exp2 sum, no online max -----------
__global__ __launch_bounds__(256) void sink_iter(
    const f16* __restrict__ K, const float* __restrict__ phi_in,
    float* __restrict__ phi_out)
{
    int lane = threadIdx.x & 63;
    int gw = (blockIdx.x << 2) + (threadIdx.x >> 6);  // global wave id, 4 rows/wave
    int b  = gw >> 9;
    int i0 = (gw & 511) << 2;
    const float* phib = phi_in + (b << 11);
    float c[32];                                      // this lane's phi slice (reused 4 rows)
    #pragma unroll
    for (int k = 0; k < 4; ++k){
        float4 p0 = *(const float4*)(phib + k * 512 + lane * 8);
        float4 p1 = *(const float4*)(phib + k * 512 + lane * 8 + 4);
        c[k*8+0]=p0.x; c[k*8+1]=p0.y; c[k*8+2]=p0.z; c[k*8+3]=p0.w;
        c[k*8+4]=p1.x; c[k*8+5]=p1.y; c[k*8+6]=p1.z; c[k*8+7]=p1.w;
    }
    float phiold[4];
    #pragma unroll
    for (int r = 0; r < 4; ++r) phiold[r] = phib[i0 + r];
    const f16* Kb = K + (((size_t)(b << 11) + i0) << 11) + lane * 8;
    #pragma unroll
    for (int r = 0; r < 4; ++r){
        const f16* Kr = Kb + ((size_t)r << 11);
        f16x8 kv0 = *(const f16x8*)(Kr);
        f16x8 kv1 = *(const f16x8*)(Kr + 512);
        f16x8 kv2 = *(const f16x8*)(Kr + 1024);
        f16x8 kv3 = *(const f16x8*)(Kr + 1536);
        float s0 = 0.f, s1 = 0.f, s2 = 0.f, s3 = 0.f;
        #pragma unroll
        for (int e = 0; e < 8; ++e){
            s0 += EX2((float)kv0[e] + c[e]);
            s1 += EX2((float)kv1[e] + c[8 + e]);
            s2 += EX2((float)kv2[e] + c[16 + e]);
            s3 += EX2((float)kv3[e] + c[24 + e]);
        }
        float s = (s0 + s1) + (s2 + s3);
        #pragma unroll
        for (int mask = 32; mask; mask >>= 1) s += __shfl_xor(s, mask);
        float gamma = -LG2(s);
        if (lane == 0) phi_out[(b << 11) + i0 + r] = 0.5f * (phiold[r] + gamma);
    }
}

// ---------------- cross logsumexp, j-split 4x, partial sums ----------------------
__global__ __launch_bounds__(256) void cross_kernel(
    const float* __restrict__ tpos, const float* __restrict__ pos,
    const float* __restrict__ phi,  const float* __restrict__ lam,
    const float* __restrict__ tss,  const float* __restrict__ pss,
    float* __restrict__ psum)
{
    __shared__ __align__(16) float As[64][68];
    __shared__ __align__(16) float Bs[64][68];
    int tt = blockIdx.x, jc = blockIdx.y, b = blockIdx.z;
    int t = threadIdx.x, tx = t & 15, ty = t >> 4;
    const float* pA = tpos + ((size_t)b * 2048 + tt * 64) * 64;
    #pragma unroll
    for (int k = 0; k < 4; ++k){
        int n = t + (k << 8);
        int r = n >> 4, d4 = (n & 15) << 2;
        float4 av = *(const float4*)(pA + r * 64 + d4);
        As[d4+0][r] = av.x; As[d4+1][r] = av.y; As[d4+2][r] = av.z; As[d4+3][r] = av.w;
    }
    float4 sv = *(const float4*)(tss + b * 2048 + tt * 64 + (ty << 2));
    float sit[4] = {sv.x, sv.y, sv.z, sv.w};
    float s[4] = {0.f, 0.f, 0.f, 0.f};

    for (int jj = 0; jj < 8; ++jj){
        int jt = (jc << 3) + jj;
        __syncthreads();
        const float* pB = pos + ((size_t)b * 2048 + jt * 64) * 64;
        #pragma unroll
        for (int k = 0; k < 4; ++k){
            int n = t + (k << 8);
            int r = n >> 4, d4 = (n & 15) << 2;
            float4 bv = *(const float4*)(pB + r * 64 + d4);
            Bs[d4+0][r] = bv.x; Bs[d4+1][r] = bv.y; Bs[d4+2][r] = bv.z; Bs[d4+3][r] = bv.w;
        }
        __syncthreads();
        float acc[4][4] = {};
        #pragma unroll 8
        for (int d = 0; d < 64; ++d){
            float4 a = *(const float4*)&As[d][ty << 2];
            float4 c = *(const float4*)&Bs[d][tx << 2];
            float aa[4] = {a.x, a.y, a.z, a.w};
            float bb[4] = {c.x, c.y, c.z, c.w};
            #pragma unroll
            for (int r = 0; r < 4; ++r)
                #pragma unroll
                for (int cc = 0; cc < 4; ++cc)
                    acc[r][cc] += aa[r] * bb[cc];
        }
        float4 v1 = *(const float4*)(pss + b * 2048 + jt * 64 + (tx << 2));
        float4 v2 = *(const float4*)(phi + b * 2048 + jt * 64 + (tx << 2));
        float4 v3 = *(const float4*)(lam + b * 2048 + jt * 64 + (tx << 2));
        float sj[4] = {v1.x, v1.y, v1.z, v1.w};
        float cj[4] = {v2.x + v3.x, v2.y + v3.y, v2.z + v3.z, v2.w + v3.w};
        #pragma unroll
        for (int r = 0; r < 4; ++r){
            #pragma unroll
            for (int c = 0; c < 4; ++c)
                s[r] += EX2((acc[r][c] - sit[r] - sj[c]) * LOG2E + cj[c]);
        }
    }
    // sum across the 16 tx lanes sharing each row
    #pragma unroll
    for (int r = 0; r < 4; ++r){
        #pragma unroll
        for (int mask = 8; mask; mask >>= 1) s[r] += __shfl_xor(s[r], mask);
    }
    if (tx == 0){
        #pragma unroll
        for (int r = 0; r < 4; ++r){
            int row = (b << 11) + tt * 64 + (ty << 2) + r;
            psum[(size_t)row * 4 + jc] = s[r];
        }
    }
}

// ---------------- finish: merge partials, weight, reduce to 8 scalars ------------
__global__ __launch_bounds__(256) void finish_kernel(
    const float* __restrict__ psum, const float* __restrict__ tlw,
    float* __restrict__ out)
{
    int b = blockIdx.x, t = threadIdx.x;
    float acc = 0.f;
    #pragma unroll
    for (int k = 0; k < 8; ++k){
        int row = t * 8 + k;           // 0..2047
        const float* p = psum + ((size_t)((b << 11) + row)) * 4;
        float s = (p[0] + p[1]) + (p[2] + p[3]);
        float g = -LG2(s) * LN2;
        acc += g * EX2(tlw[(b << 11) + row] * LOG2E);
    }
    __shared__ float red[256];
    red[t] = acc; __syncthreads();
    for (int off = 128; off; off >>= 1){
        if (t < off) red[t] += red[t + off];
        __syncthreads();
    }
    if (t == 0) out[b] = red[0];
}

// ---------------- launch ---------------------------------------------------------
extern "C" void kernel_launch(void* const* d_in, const int* in_sizes, int n_in,
                              void* d_out, int out_size, void* d_ws, size_t ws_size,
                              hipStream_t stream)
{
    const float* pos  = (const float*)d_in[0];
    const float* lw   = (const float*)d_in[1];
    const float* tpos = (const float*)d_in[2];
    const float* tlw  = (const float*)d_in[3];
    float* out = (float*)d_out;

    char* ws = (char*)d_ws;
    f16* K = (f16*)ws;
    size_t off = (size_t)8 * 2048 * 2048 * 2;          // 67,108,864 B
    float* phi0 = (float*)(ws + off); off += 65536;
    float* phi1 = (float*)(ws + off); off += 65536;
    float* lam  = (float*)(ws + off); off += 65536;
    float* pss  = (float*)(ws + off); off += 65536;
    float* tss  = (float*)(ws + off); off += 65536;
    float* psum = (float*)(ws + off); off += 16384 * 4 * sizeof(float);

    prep_kernel<<<64, 256, 0, stream>>>(lw, pos, tpos, lam, phi0, pss, tss);
    build_kself<<<dim3(32, 32, 8), 256, 0, stream>>>(pos, lam, pss, K);

    float* pin = phi0; float* pout = phi1;
    for (int it = 0; it < 100; ++it){
        sink_iter<<<1024, 256, 0, stream>>>(K, pin, pout);
        float* tmp = pin; pin = pout; pout = tmp;
    }
    cross_kernel<<<dim3(32, 4, 8), 256, 0, stream>>>(tpos, pos, pin, lam, tss, pss, psum);
    finish_kernel<<<8, 256, 0, stream>>>(psum, tlw, out);
}

// Round 4
// 1071.436 us; speedup vs baseline: 1.3884x; 1.3113x over previous
//
#include <hip/hip_runtime.h>
#include <math.h>

// Symmetric-factorized Sinkhorn fixed point, exp2 domain:
//   kappa[b,i,j] = (dot_ij - ss_i - ss_j)*log2e = -|xi-xj|^2/2*log2e  <= 0, symmetric
//   (fp16, tile-packed upper triangle, 35.7MB; EX2(kappa) <= 1, never inf)
//   rowsum_i = sum_j 2^kappa_ij * u_j,  u_j = 2^(phi_j + lam_j)   (diag term = u_i > 0)
//   gamma_i = -log2(rowsum_i);  phi' = 0.5(phi + gamma)
//   phi-update folded into next iteration's kernel (3-buffer rowsum rotation);
//   each upper-triangle tile feeds both row sums (p*u_j) and col sums (p*u_i).

typedef _Float16 f16;
typedef _Float16 f16x4 __attribute__((ext_vector_type(4)));
typedef _Float16 f16x8 __attribute__((ext_vector_type(8)));

#define LOG2E 1.4426950408889634f
#define LN2   0.6931471805599453f
#define NT    16          // 128-tiles per dim
#define NTRI  136         // NT*(NT+1)/2

__device__ __forceinline__ float EX2(float x){
#if __has_builtin(__builtin_amdgcn_exp2f)
    return __builtin_amdgcn_exp2f(x);
#else
    float r; asm("v_exp_f32 %0, %1" : "=v"(r) : "v"(x)); return r;
#endif
}
__device__ __forceinline__ float LG2(float x){
#if __has_builtin(__builtin_amdgcn_logf)
    return __builtin_amdgcn_logf(x);
#else
    float r; asm("v_log_f32 %0, %1" : "=v"(r) : "v"(x)); return r;
#endif
}

// ---------------- prep: lam, phi0=0, rowsum0=0, half-sum-of-squares --------------
__global__ __launch_bounds__(256) void prep_kernel(
    const float* __restrict__ lw, const float* __restrict__ pos,
    const float* __restrict__ tpos, float* __restrict__ lam,
    float* __restrict__ phi0, float* __restrict__ pss, float* __restrict__ tss,
    float* __restrict__ R0)
{
    int idx = blockIdx.x * 256 + threadIdx.x;   // 0..16383
    lam[idx]  = lw[idx] * LOG2E;
    phi0[idx] = 0.f;
    R0[idx]   = 0.f;
    const float4* pr = (const float4*)(pos + (size_t)idx * 64);
    float s = 0.f;
    #pragma unroll
    for (int k = 0; k < 16; ++k){ float4 v = pr[k]; s += v.x*v.x + v.y*v.y + v.z*v.z + v.w*v.w; }
    pss[idx] = 0.5f * s;
    const float4* tr = (const float4*)(tpos + (size_t)idx * 64);
    float s2 = 0.f;
    #pragma unroll
    for (int k = 0; k < 16; ++k){ float4 v = tr[k]; s2 += v.x*v.x + v.y*v.y + v.z*v.z + v.w*v.w; }
    tss[idx] = 0.5f * s2;
}

// ---------------- build kappa = (dot-ssi-ssj)*log2e, tile-packed triangle --------
// grid.x = NTRI*4 (136 128-tiles x 4 64-subtiles), grid.y = batch
__global__ __launch_bounds__(256) void build_packed(
    const float* __restrict__ pos, const float* __restrict__ pss,
    f16* __restrict__ S)
{
    __shared__ __align__(16) float As[64][64];   // transposed: As[d][r]
    __shared__ __align__(16) float Bs[64][64];
    int sub = blockIdx.x & 3, tile = blockIdx.x >> 2, b = blockIdx.y;
    int it = 0, rem = tile;
    while (rem >= NT - it){ rem -= NT - it; ++it; }
    int jt = it + rem;
    int ra = sub >> 1, cb2 = sub & 1;                  // 64-row half, 64-col half
    int i64 = (it << 1) + ra, j64 = (jt << 1) + cb2;   // global 64-tile coords
    int t = threadIdx.x;
    const float* pA = pos + ((size_t)b * 2048 + i64 * 64) * 64;
    const float* pB = pos + ((size_t)b * 2048 + j64 * 64) * 64;
    #pragma unroll
    for (int k = 0; k < 4; ++k){
        int n = t + (k << 8);
        int r = n & 63, d4 = (n >> 6) << 2;           // conflict-free staging
        float4 av = *(const float4*)(pA + r * 64 + d4);
        As[d4+0][r] = av.x; As[d4+1][r] = av.y; As[d4+2][r] = av.z; As[d4+3][r] = av.w;
        float4 bv = *(const float4*)(pB + r * 64 + d4);
        Bs[d4+0][r] = bv.x; Bs[d4+1][r] = bv.y; Bs[d4+2][r] = bv.z; Bs[d4+3][r] = bv.w;
    }
    __syncthreads();
    int tx = t & 15, ty = t >> 4;
    float acc[4][4] = {};
    #pragma unroll 8
    for (int d = 0; d < 64; ++d){
        float4 a = *(const float4*)&As[d][ty << 2];
        float4 c = *(const float4*)&Bs[d][tx << 2];
        float aa[4] = {a.x, a.y, a.z, a.w};
        float bb[4] = {c.x, c.y, c.z, c.w};
        #pragma unroll
        for (int r = 0; r < 4; ++r)
            #pragma unroll
            for (int cc = 0; cc < 4; ++cc)
                acc[r][cc] += aa[r] * bb[cc];
    }
    float4 siv = *(const float4*)(pss + b * 2048 + i64 * 64 + (ty << 2));
    float4 sjv = *(const float4*)(pss + b * 2048 + j64 * 64 + (tx << 2));
    float si[4] = {siv.x, siv.y, siv.z, siv.w};
    float sj[4] = {sjv.x, sjv.y, sjv.z, sjv.w};
    f16* tb = S + ((size_t)(b * NTRI + tile) << 14);   // 128x128 packed tile
    #pragma unroll
    for (int r = 0; r < 4; ++r){
        f16x4 o;
        #pragma unroll
        for (int c = 0; c < 4; ++c)
            o[c] = (f16)((acc[r][c] - si[r] - sj[c]) * LOG2E);
        int rl = (ra << 6) + (ty << 2) + r;
        int cl = (cb2 << 6) + (tx << 2);
        *(f16x4*)(tb + rl * 128 + cl) = o;
    }
}

// ---------------- one iteration: phi-update + symmetric tile accumulation --------
__global__ __launch_bounds__(256) void sink_sym(
    const f16* __restrict__ S, const float* __restrict__ phiPrev,
    float* __restrict__ phiCur, const float* __restrict__ Rprev,
    float* __restrict__ Rcur, float* __restrict__ Rnext,
    const float* __restrict__ lam, int k)
{
    __shared__ float vi_s[128], vj_s[128];
    __shared__ float cbuf[4][128];
    int tile = blockIdx.x, b = blockIdx.y;
    int it = 0, rem = tile;
    while (rem >= NT - it){ rem -= NT - it; ++it; }
    int jt = it + rem;
    int it0 = it << 7, jt0 = jt << 7;
    bool diag = (it == jt);
    int t = threadIdx.x;

    // zero this block's share of the iteration-after-next rowsum buffer
    {
        int z = (b * NTRI + tile) * 16 + t;
        if (t < 16 && z < 16384) Rnext[z] = 0.f;
    }
    // phi update + u for this tile's row & col ranges (redundant across blocks,
    // deterministic; diagonal blocks persist phi)
    {
        bool isRow = t < 128;
        int loc = isRow ? (it0 + t) : (jt0 + (t - 128));
        int g = (b << 11) + loc;
        float ph = 0.f;
        if (k > 0){
            float gam = -LG2(Rprev[g]);
            ph = 0.5f * (phiPrev[g] + gam);
        }
        float v = EX2(ph + lam[g]);
        if (isRow){
            vi_s[t] = v;
            if (diag && k > 0) phiCur[g] = ph;
        } else {
            vj_s[t - 128] = v;
        }
    }
    __syncthreads();

    int tx = t & 7, ty = t >> 3;        // tx: 8 groups of 16 cols; ty: 32 groups of 4 rows
    float vj[16];
    #pragma unroll
    for (int c4 = 0; c4 < 4; ++c4){
        float4 v4 = *(const float4*)&vj_s[tx * 16 + c4 * 4];
        vj[c4*4+0] = v4.x; vj[c4*4+1] = v4.y; vj[c4*4+2] = v4.z; vj[c4*4+3] = v4.w;
    }
    float4 vi4 = *(const float4*)&vi_s[ty * 4];
    float vi[4] = {vi4.x, vi4.y, vi4.z, vi4.w};

    const f16* tb = S + ((size_t)(b * NTRI + tile) << 14);
    const f16* Sp = tb + (ty * 4) * 128 + tx * 16;
    float rowp[4];
    float colp[16];
    #pragma unroll
    for (int c = 0; c < 16; ++c) colp[c] = 0.f;

    #pragma unroll
    for (int r = 0; r < 4; ++r){
        f16x8 a0 = *(const f16x8*)(Sp + r * 128);
        f16x8 a1 = *(const f16x8*)(Sp + r * 128 + 8);
        float p[16];
        #pragma unroll
        for (int e = 0; e < 8; ++e){ p[e] = EX2((float)a0[e]); p[8+e] = EX2((float)a1[e]); }
        float rp = 0.f;
        #pragma unroll
        for (int c = 0; c < 16; ++c){
            rp = fmaf(p[c], vj[c], rp);
            if (!diag) colp[c] = fmaf(p[c], vi[r], colp[c]);
        }
        rowp[r] = rp;
    }
    // row-sum reduce across the 8 tx lanes
    #pragma unroll
    for (int m = 1; m <= 4; m <<= 1)
        #pragma unroll
        for (int r = 0; r < 4; ++r) rowp[r] += __shfl_xor(rowp[r], m);
    if (tx == 0){
        #pragma unroll
        for (int r = 0; r < 4; ++r)
            atomicAdd(&Rcur[(b << 11) + it0 + ty * 4 + r], rowp[r]);
    }
    if (!diag){
        // col-sum reduce across ty-within-wave (lanes xor 8,16,32), then across waves via LDS
        #pragma unroll
        for (int m = 8; m <= 32; m <<= 1)
            #pragma unroll
            for (int c = 0; c < 16; ++c) colp[c] += __shfl_xor(colp[c], m);
        int w = t >> 6;
        if ((t & 63) < 8){
            #pragma unroll
            for (int c = 0; c < 16; ++c) cbuf[w][(t & 7) * 16 + c] = colp[c];
        }
        __syncthreads();
        if (t < 128){
            float s = (cbuf[0][t] + cbuf[1][t]) + (cbuf[2][t] + cbuf[3][t]);
            atomicAdd(&Rcur[(b << 11) + jt0 + t], s);
        }
    }
}

// ---------------- finalize: phi^(100), cj = phi + lam ----------------------------
__global__ __launch_bounds__(256) void finalize_phi(
    const float* __restrict__ phiPrev, const float* __restrict__ Rlast,
    const float* __restrict__ lam, float* __restrict__ cj)
{
    int g = blockIdx.x * 256 + threadIdx.x;
    float gam = -LG2(Rlast[g]);
    float ph = 0.5f * (phiPrev[g] + gam);
    cj[g] = ph + lam[g];
}

// ---------------- cross logsumexp, j-split 8x, partial sums ----------------------
__global__ __launch_bounds__(256) void cross_kernel(
    const float* __restrict__ tpos, const float* __restrict__ pos,
    const float* __restrict__ cj,   const float* __restrict__ tss,
    const float* __restrict__ pss,  float* __restrict__ psum)
{
    __shared__ __align__(16) float As[64][64];
    __shared__ __align__(16) float Bs[64][64];
    int tt = blockIdx.x, jc = blockIdx.y, b = blockIdx.z;
    int t = threadIdx.x, tx = t & 15, ty = t >> 4;
    const float* pA = tpos + ((size_t)b * 2048 + tt * 64) * 64;
    #pragma unroll
    for (int k = 0; k < 4; ++k){
        int n = t + (k << 8);
        int r = n & 63, d4 = (n >> 6) << 2;
        float4 av = *(const float4*)(pA + r * 64 + d4);
        As[d4+0][r] = av.x; As[d4+1][r] = av.y; As[d4+2][r] = av.z; As[d4+3][r] = av.w;
    }
    float4 sv = *(const float4*)(tss + b * 2048 + tt * 64 + (ty << 2));
    float sit[4] = {sv.x, sv.y, sv.z, sv.w};
    float s[4] = {0.f, 0.f, 0.f, 0.f};

    for (int jj = 0; jj < 4; ++jj){
        int jt = (jc << 2) + jj;
        __syncthreads();
        const float* pB = pos + ((size_t)b * 2048 + jt * 64) * 64;
        #pragma unroll
        for (int k = 0; k < 4; ++k){
            int n = t + (k << 8);
            int r = n & 63, d4 = (n >> 6) << 2;
            float4 bv = *(const float4*)(pB + r * 64 + d4);
            Bs[d4+0][r] = bv.x; Bs[d4+1][r] = bv.y; Bs[d4+2][r] = bv.z; Bs[d4+3][r] = bv.w;
        }
        __syncthreads();
        float acc[4][4] = {};
        #pragma unroll 8
        for (int d = 0; d < 64; ++d){
            float4 a = *(const float4*)&As[d][ty << 2];
            float4 c = *(const float4*)&Bs[d][tx << 2];
            float aa[4] = {a.x, a.y, a.z, a.w};
            float bb[4] = {c.x, c.y, c.z, c.w};
            #pragma unroll
            for (int r = 0; r < 4; ++r)
                #pragma unroll
                for (int cc = 0; cc < 4; ++cc)
                    acc[r][cc] += aa[r] * bb[cc];
        }
        float4 v1 = *(const float4*)(pss + b * 2048 + jt * 64 + (tx << 2));
        float4 v2 = *(const float4*)(cj  + b * 2048 + jt * 64 + (tx << 2));
        float sj[4] = {v1.x, v1.y, v1.z, v1.w};
        float cjv[4] = {v2.x, v2.y, v2.z, v2.w};
        #pragma unroll
        for (int r = 0; r < 4; ++r){
            #pragma unroll
            for (int c = 0; c < 4; ++c)
                s[r] += EX2((acc[r][c] - sit[r] - sj[c]) * LOG2E + cjv[c]);
        }
    }
    #pragma unroll
    for (int r = 0; r < 4; ++r){
        #pragma unroll
        for (int mask = 8; mask; mask >>= 1) s[r] += __shfl_xor(s[r], mask);
    }
    if (tx == 0){
        #pragma unroll
        for (int r = 0; r < 4; ++r){
            int row = (b << 11) + tt * 64 + (ty << 2) + r;
            psum[(size_t)row * 8 + jc] = s[r];
        }
    }
}

// ---------------- finish: merge partials, weight, reduce to 8 scalars ------------
__global__ __launch_bounds__(256) void finish_kernel(
    const float* __restrict__ psum, const float* __restrict__ tlw,
    float* __restrict__ out)
{
    int b = blockIdx.x, t = threadIdx.x;
    float acc = 0.f;
    #pragma unroll
    for (int k = 0; k < 8; ++k){
        int row = t * 8 + k;
        const float* p = psum + ((size_t)((b << 11) + row)) * 8;
        float s = ((p[0] + p[1]) + (p[2] + p[3])) + ((p[4] + p[5]) + (p[6] + p[7]));
        float g = -LG2(s) * LN2;
        acc += g * EX2(tlw[(b << 11) + row] * LOG2E);
    }
    __shared__ float red[256];
    red[t] = acc; __syncthreads();
    for (int off = 128; off; off >>= 1){
        if (t < off) red[t] += red[t + off];
        __syncthreads();
    }
    if (t == 0) out[b] = red[0];
}

// ---------------- launch ---------------------------------------------------------
extern "C" void kernel_launch(void* const* d_in, const int* in_sizes, int n_in,
                              void* d_out, int out_size, void* d_ws, size_t ws_size,
                              hipStream_t stream)
{
    const float* pos  = (const float*)d_in[0];
    const float* lw   = (const float*)d_in[1];
    const float* tpos = (const float*)d_in[2];
    const float* tlw  = (const float*)d_in[3];
    float* out = (float*)d_out;

    char* ws = (char*)d_ws;
    f16* S = (f16*)ws;
    size_t off = (size_t)8 * NTRI * 16384 * 2;         // 35,651,584 B packed triangle
    float* P0  = (float*)(ws + off); off += 65536;
    float* P1  = (float*)(ws + off); off += 65536;
    float* R0  = (float*)(ws + off); off += 65536;
    float* R1  = (float*)(ws + off); off += 65536;
    float* R2  = (float*)(ws + off); off += 65536;
    float* lam = (float*)(ws + off); off += 65536;
    float* pss = (float*)(ws + off); off += 65536;
    float* tss = (float*)(ws + off); off += 65536;
    float* cj  = (float*)(ws + off); off += 65536;
    float* psum = (float*)(ws + off); off += (size_t)16384 * 8 * 4;

    prep_kernel<<<64, 256, 0, stream>>>(lw, pos, tpos, lam, P0, pss, tss, R0);
    build_packed<<<dim3(NTRI * 4, 8), 256, 0, stream>>>(pos, pss, S);

    float* Rb[3] = {R0, R1, R2};
    float* Pb[2] = {P0, P1};
    for (int k = 0; k < 100; ++k){
        sink_sym<<<dim3(NTRI, 8), 256, 0, stream>>>(
            S, Pb[(k + 1) & 1], Pb[k & 1],
            Rb[(k + 2) % 3], Rb[k % 3], Rb[(k + 1) % 3],
            lam, k);
    }
    finalize_phi<<<64, 256, 0, stream>>>(Pb[1], Rb[0], lam, cj);
    cross_kernel<<<dim3(32, 8, 8), 256, 0, stream>>>(tpos, pos, cj, tss, pss, psum);
    finish_kernel<<<8, 256, 0, stream>>>(psum, tlw, out);
}